// Round 6
// baseline (2477.675 us; speedup 1.0000x reference)
//
#include <hip/hip_runtime.h>
#include <math.h>

typedef float f32x4 __attribute__((ext_vector_type(4)));

// ---------------------------------------------------------------------------
// Kernel 1: row normalization (4 rows per block, one per wave) + workspace
// zeroing fused in. Output: fp8 e4m3 (OCP) rows for the MFMA pass.
__global__ __launch_bounds__(256) void norm_kernel(
    const float* __restrict__ X, unsigned char* __restrict__ Y8,
    float* __restrict__ unsim, float* __restrict__ accum, float inv_sqrtT) {
  int t = threadIdx.x;
  int w = t >> 6, lane = t & 63;
  int row = blockIdx.x * 4 + w;
  float2 v = ((const float2*)(X + (size_t)row * 128))[lane];
  float s = v.x * v.x + v.y * v.y;
#pragma unroll
  for (int m = 1; m < 64; m <<= 1) s += __shfl_xor(s, m);
  float inv = inv_sqrtT * rsqrtf(fmaxf(s, 1e-24f));
  // pack 2 fp8 e4m3 bytes (RNE)
  int packed =
      __builtin_amdgcn_cvt_pk_fp8_f32(v.x * inv, v.y * inv, 0, false);
  ((unsigned short*)(Y8 + (size_t)row * 128))[lane] =
      (unsigned short)(packed & 0xffff);
  // zero 4 unsim entries per block; block 0 zeroes accum + pcur slots
  if (t < 4) unsim[blockIdx.x * 4 + t] = 0.f;
  if (blockIdx.x == 0 && t < 8) accum[t] = 0.f;  // accum[0..5] + pcur(6..7)
}

// ---------------------------------------------------------------------------
// Kernel 2: fp8 MFMA similarity pass over upper-triangular 128x128 tile
// pairs (R4 structure, fp8 tiles -> 39 KB LDS -> 4 blocks/CU).
// Fused: exp + label-mask row/col sums (LDS-staged, ONE global atomic per
// row per block) + positive-pair (idx,s) records straight to global.
__global__ __launch_bounds__(256, 4) void pass1_kernel(
    const unsigned char* __restrict__ Y8, const int* __restrict__ lab,
    float* __restrict__ unsim, uint2* __restrict__ posBuf,
    int* __restrict__ pcur, int nt) {
  __shared__ unsigned char As[128][144];  // +16B pad: 2-way conflicts (free)
  __shared__ unsigned char Bs[128][144];
  __shared__ int labR[128], labC[128];
  __shared__ float rsumS[128], csumS[128];

  // decode linear block id -> (bi, bj), bi <= bj (triangular)
  int b = blockIdx.x;
  float ntf = (float)nt;
  int bi = (int)((2.f * ntf + 1.f -
                  sqrtf((2.f * ntf + 1.f) * (2.f * ntf + 1.f) - 8.f * (float)b)) *
                 0.5f);
  if (bi < 0) bi = 0;
  while ((bi + 1) * nt - ((bi + 1) * bi) / 2 <= b) ++bi;
  while (bi * nt - (bi * (bi - 1)) / 2 > b) --bi;
  int bj = bi + (b - (bi * nt - (bi * (bi - 1)) / 2));
  const int i0 = bi * 128, j0 = bj * 128;
  const bool offdiag = (bi != bj);

  const int t = threadIdx.x;
  const float4* Yg = (const float4*)Y8;  // row = 8 float4 chunks (128 B)
#pragma unroll
  for (int c = t; c < 1024; c += 256) {
    int row = c >> 3, kc = c & 7;
    *(float4*)&As[row][kc * 16] = Yg[(size_t)(i0 + row) * 8 + kc];
    *(float4*)&Bs[row][kc * 16] = Yg[(size_t)(j0 + row) * 8 + kc];
  }
  if (t < 128) {
    labR[t] = lab[i0 + t];
    labC[t] = lab[j0 + t];
    rsumS[t] = 0.f;
    csumS[t] = 0.f;
  }
  __syncthreads();

  const int w = t >> 6, lane = t & 63;
  const int quad = lane >> 4, l16 = lane & 15;
  const int rbase = (w >> 1) * 64, cbase = (w & 1) * 64;

  f32x4 acc[4][4] = {};
#pragma unroll
  for (int ks = 0; ks < 4; ++ks) {
    const int kof = ks * 32 + quad * 8;  // byte offset into the K=128 row
    long af[4], bf[4];
#pragma unroll
    for (int p = 0; p < 4; ++p)
      af[p] = *(const long*)&As[rbase + p * 16 + l16][kof];
#pragma unroll
    for (int p = 0; p < 4; ++p)
      bf[p] = *(const long*)&Bs[cbase + p * 16 + l16][kof];
#pragma unroll
    for (int pi = 0; pi < 4; ++pi)
#pragma unroll
      for (int pj = 0; pj < 4; ++pj)
        acc[pi][pj] = __builtin_amdgcn_mfma_f32_16x16x32_fp8_fp8(
            af[pi], bf[pj], acc[pi][pj], 0, 0, 0);
  }

  // ---- epilogue ----
  int lr[4][4], lc[4];
#pragma unroll
  for (int pi = 0; pi < 4; ++pi)
#pragma unroll
    for (int r = 0; r < 4; ++r) lr[pi][r] = labR[rbase + pi * 16 + quad * 4 + r];
#pragma unroll
  for (int pj = 0; pj < 4; ++pj) lc[pj] = labC[cbase + pj * 16 + l16];

  float rowp[4][4] = {};
  float colp[4] = {0.f, 0.f, 0.f, 0.f};
#pragma unroll
  for (int pi = 0; pi < 4; ++pi)
#pragma unroll
    for (int pj = 0; pj < 4; ++pj)
#pragma unroll
      for (int r = 0; r < 4; ++r) {
        const bool same = (lr[pi][r] == lc[pj]);
        float s = acc[pi][pj][r];
        float e = same ? 0.f : __expf(s);
        rowp[pi][r] += e;
        colp[pj] += e;
        if (same) {  // rare (~1/128): direct global append, no LDS staging
          const int gi = i0 + rbase + pi * 16 + quad * 4 + r;
          const int gj = j0 + cbase + pj * 16 + l16;
          if (offdiag || (gi != gj)) {
            int nadd = offdiag ? 2 : 1;
            int s0 = atomicAdd(pcur, nadd);
            unsigned sb = __float_as_uint(s);
            uint2 e0 = {(unsigned)gi, sb};
            posBuf[s0] = e0;
            if (offdiag) {
              uint2 e1 = {(unsigned)gj, sb};
              posBuf[s0 + 1] = e1;
            }
          }
        }
      }

  // row sums: 4-shfl reduce over the 16 cols, stage in LDS
#pragma unroll
  for (int pi = 0; pi < 4; ++pi)
#pragma unroll
    for (int r = 0; r < 4; ++r) {
      float v = rowp[pi][r];
      v += __shfl_xor(v, 1);
      v += __shfl_xor(v, 2);
      v += __shfl_xor(v, 4);
      v += __shfl_xor(v, 8);
      if (l16 == 0) atomicAdd(&rsumS[rbase + pi * 16 + quad * 4 + r], v);
    }
  // col sums (mirror band): reduce across quads, stage in LDS
#pragma unroll
  for (int pj = 0; pj < 4; ++pj) {
    float v = colp[pj];
    v += __shfl_xor(v, 16);
    v += __shfl_xor(v, 32);
    if (quad == 0) atomicAdd(&csumS[cbase + pj * 16 + l16], v);
  }
  __syncthreads();

  // flush: ONE global atomic per row (and per col if off-diagonal)
  if (t < 128) {
    atomicAdd(&unsim[i0 + t], rsumS[t]);
  } else if (offdiag) {
    atomicAdd(&unsim[j0 + (t - 128)], csumS[t - 128]);
  }
}

// ---------------------------------------------------------------------------
// Kernel 3: stream positive records: term = log(exp(s) + unsim[idx]) - s,
// finalize fused via last-block-done pattern.
__global__ __launch_bounds__(256) void pass3_kernel(
    const uint2* __restrict__ posBuf, int* __restrict__ pcur,
    const float* __restrict__ unsim, float* __restrict__ accum,
    float* __restrict__ out) {
  int n = *pcur;
  float local = 0.f;
  int stride = 256 * gridDim.x;
  for (int p = blockIdx.x * 256 + threadIdx.x; p < n; p += stride) {
    uint2 e = posBuf[p];
    float s = __uint_as_float(e.y);
    local += logf(__expf(s) + unsim[e.x]) - s;
  }
  __shared__ float red[4];
#pragma unroll
  for (int msk = 1; msk < 64; msk <<= 1) local += __shfl_xor(local, msk);
  int lane = threadIdx.x & 63, w = threadIdx.x >> 6;
  if (lane == 0) red[w] = local;
  __syncthreads();
  if (threadIdx.x == 0) {
    atomicAdd(&accum[0], red[0] + red[1] + red[2] + red[3]);
    __threadfence();
    int* done = (int*)&accum[2];
    if (atomicAdd(done, 1) == (int)gridDim.x - 1) {
      float ls = __hip_atomic_load(&accum[0], __ATOMIC_ACQUIRE,
                                   __HIP_MEMORY_SCOPE_AGENT);
      out[0] = ls / (float)n;
    }
  }
}

// ---------------------------------------------------------------------------
extern "C" void kernel_launch(void* const* d_in, const int* in_sizes, int n_in,
                              void* d_out, int out_size, void* d_ws,
                              size_t ws_size, hipStream_t stream) {
  const float* X = (const float*)d_in[0];
  const int* lab = (const int*)d_in[1];
  float* out = (float*)d_out;

  const int N = in_sizes[1];  // 8192; D fixed at 128

  // workspace layout
  unsigned char* Y8 = (unsigned char*)d_ws;       // N*128 fp8 (1 MB)
  float* unsim = (float*)(Y8 + (size_t)N * 128);  // N f32
  float* accum = unsim + N;                       // [0] loss, [2] done ctr
  int* pcur = (int*)(accum + 6);                  // record cursor (+ pad)
  uint2* posBuf = (uint2*)(pcur + 2);             // ~516k entries

  const float inv_sqrtT = 2.2360679775f;  // 1/sqrt(0.2)
  norm_kernel<<<N / 4, 256, 0, stream>>>(X, Y8, unsim, accum, inv_sqrtT);

  const int nt = N / 128;              // 64 tiles per dim
  const int nblk = nt * (nt + 1) / 2;  // 2080 upper-tri tile pairs
  pass1_kernel<<<nblk, 256, 0, stream>>>(Y8, lab, unsim, posBuf, pcur, nt);
  pass3_kernel<<<512, 256, 0, stream>>>(posBuf, pcur, unsim, accum, out);
}

// Round 7
// 133.926 us; speedup vs baseline: 18.5003x; 18.5003x over previous
//
#include <hip/hip_runtime.h>
#include <math.h>

#define PCAP 512  // per-block LDS positive-pair staging capacity

typedef float f32x4 __attribute__((ext_vector_type(4)));

// ---------------------------------------------------------------------------
// Kernel 1: row normalization (4 rows per block, one per wave) + workspace
// zeroing fused in. Output: fp8 e4m3 (OCP) rows for the MFMA pass.
__global__ __launch_bounds__(256) void norm_kernel(
    const float* __restrict__ X, unsigned char* __restrict__ Y8,
    float* __restrict__ unsim, float* __restrict__ accum, float inv_sqrtT) {
  int t = threadIdx.x;
  int w = t >> 6, lane = t & 63;
  int row = blockIdx.x * 4 + w;
  float2 v = ((const float2*)(X + (size_t)row * 128))[lane];
  float s = v.x * v.x + v.y * v.y;
#pragma unroll
  for (int m = 1; m < 64; m <<= 1) s += __shfl_xor(s, m);
  float inv = inv_sqrtT * rsqrtf(fmaxf(s, 1e-24f));
  int packed = __builtin_amdgcn_cvt_pk_fp8_f32(v.x * inv, v.y * inv, 0, false);
  ((unsigned short*)(Y8 + (size_t)row * 128))[lane] =
      (unsigned short)(packed & 0xffff);
  if (t < 4) unsim[blockIdx.x * 4 + t] = 0.f;
  if (blockIdx.x == 0 && t < 8) accum[t] = 0.f;  // accum[0..5] + pcur(6..7)
}

// ---------------------------------------------------------------------------
// Kernel 2: fp8 MFMA similarity pass over upper-triangular 128x128 tile
// pairs. XOR-swizzled unpadded fp8 tiles (16 KB each) -> 38.9 KB LDS ->
// 4 blocks/CU. Positives: LDS-staged append (posCnt LDS atomic; ONE global
// pcur atomic per block at flush — per-record global atomics were the R6
// 30x regression). unsim row/col sums: LDS-staged, one global atomic per
// row per block.
__global__ __launch_bounds__(256, 4) void pass1_kernel(
    const unsigned char* __restrict__ Y8, const int* __restrict__ lab,
    float* __restrict__ unsim, uint2* __restrict__ posBuf,
    int* __restrict__ pcur, int nt) {
  __shared__ unsigned char As[128][128];  // chunk c stored at (c ^ (row&7))
  __shared__ unsigned char Bs[128][128];
  __shared__ int labR[128], labC[128];
  __shared__ float rsumS[128], csumS[128];
  __shared__ uint2 posS[PCAP];
  __shared__ int posCnt, gbaseS;

  // decode linear block id -> (bi, bj), bi <= bj (triangular)
  int b = blockIdx.x;
  float ntf = (float)nt;
  int bi = (int)((2.f * ntf + 1.f -
                  sqrtf((2.f * ntf + 1.f) * (2.f * ntf + 1.f) - 8.f * (float)b)) *
                 0.5f);
  if (bi < 0) bi = 0;
  while ((bi + 1) * nt - ((bi + 1) * bi) / 2 <= b) ++bi;
  while (bi * nt - (bi * (bi - 1)) / 2 > b) --bi;
  int bj = bi + (b - (bi * nt - (bi * (bi - 1)) / 2));
  const int i0 = bi * 128, j0 = bj * 128;
  const bool offdiag = (bi != bj);

  const int t = threadIdx.x;
  const float4* Yg = (const float4*)Y8;  // row = 8 float4 chunks (128 B)
#pragma unroll
  for (int c = t; c < 1024; c += 256) {
    int row = c >> 3, kc = c & 7;
    int swc = (kc ^ (row & 7)) << 4;
    *(float4*)&As[row][swc] = Yg[(size_t)(i0 + row) * 8 + kc];
    *(float4*)&Bs[row][swc] = Yg[(size_t)(j0 + row) * 8 + kc];
  }
  if (t < 128) {
    labR[t] = lab[i0 + t];
    labC[t] = lab[j0 + t];
    rsumS[t] = 0.f;
    csumS[t] = 0.f;
  }
  if (t == 0) posCnt = 0;
  __syncthreads();

  const int w = t >> 6, lane = t & 63;
  const int quad = lane >> 4, l16 = lane & 15;
  const int rbase = (w >> 1) * 64, cbase = (w & 1) * 64;
  const int sw = l16 & 7;

  f32x4 acc[4][4] = {};
#pragma unroll
  for (int ks = 0; ks < 4; ++ks) {
    // this k-step reads 8 fp8 bytes from chunk (ks*2 + quad/2), half (quad&1)
    const int ch = ks * 2 + (quad >> 1);
    const int off = ((ch ^ sw) << 4) + ((quad & 1) << 3);
    long af[4], bf[4];
#pragma unroll
    for (int p = 0; p < 4; ++p)
      af[p] = *(const long*)&As[rbase + p * 16 + l16][off];
#pragma unroll
    for (int p = 0; p < 4; ++p)
      bf[p] = *(const long*)&Bs[cbase + p * 16 + l16][off];
#pragma unroll
    for (int pi = 0; pi < 4; ++pi)
#pragma unroll
      for (int pj = 0; pj < 4; ++pj)
        acc[pi][pj] = __builtin_amdgcn_mfma_f32_16x16x32_fp8_fp8(
            af[pi], bf[pj], acc[pi][pj], 0, 0, 0);
  }
  // NOTE: the 16x16x32 fp8 MFMA K-order within the 8-byte operand matches
  // the f16 layout byte-for-byte (K index = byte index); A and B use the
  // same row-major K-packing so dot(y_i, y_j) is computed exactly as R2-R4.

  // ---- epilogue ----
  int lr[4][4], lc[4];
#pragma unroll
  for (int pi = 0; pi < 4; ++pi)
#pragma unroll
    for (int r = 0; r < 4; ++r) lr[pi][r] = labR[rbase + pi * 16 + quad * 4 + r];
#pragma unroll
  for (int pj = 0; pj < 4; ++pj) lc[pj] = labC[cbase + pj * 16 + l16];

  float rowp[4][4] = {};
  float colp[4] = {0.f, 0.f, 0.f, 0.f};
#pragma unroll
  for (int pi = 0; pi < 4; ++pi)
#pragma unroll
    for (int pj = 0; pj < 4; ++pj)
#pragma unroll
      for (int r = 0; r < 4; ++r) {
        const bool same = (lr[pi][r] == lc[pj]);
        float s = acc[pi][pj][r];
        float e = same ? 0.f : __expf(s);
        rowp[pi][r] += e;
        colp[pj] += e;
        if (same) {  // rare (~1/128): LDS-staged append
          const int gi = i0 + rbase + pi * 16 + quad * 4 + r;
          const int gj = j0 + cbase + pj * 16 + l16;
          if (offdiag || (gi != gj)) {
            int nadd = offdiag ? 2 : 1;
            int s0 = atomicAdd(&posCnt, nadd);
            unsigned sb = __float_as_uint(s);
            uint2 e0 = {(unsigned)gi, sb};
            if (s0 < PCAP) posS[s0] = e0;
            else posBuf[atomicAdd(pcur, 1)] = e0;
            if (offdiag) {
              uint2 e1 = {(unsigned)gj, sb};
              if (s0 + 1 < PCAP) posS[s0 + 1] = e1;
              else posBuf[atomicAdd(pcur, 1)] = e1;
            }
          }
        }
      }

  // row sums: 4-shfl reduce over the 16 cols, stage in LDS
#pragma unroll
  for (int pi = 0; pi < 4; ++pi)
#pragma unroll
    for (int r = 0; r < 4; ++r) {
      float v = rowp[pi][r];
      v += __shfl_xor(v, 1);
      v += __shfl_xor(v, 2);
      v += __shfl_xor(v, 4);
      v += __shfl_xor(v, 8);
      if (l16 == 0) atomicAdd(&rsumS[rbase + pi * 16 + quad * 4 + r], v);
    }
  // col sums (mirror band): reduce across quads, stage in LDS
#pragma unroll
  for (int pj = 0; pj < 4; ++pj) {
    float v = colp[pj];
    v += __shfl_xor(v, 16);
    v += __shfl_xor(v, 32);
    if (quad == 0) atomicAdd(&csumS[cbase + pj * 16 + l16], v);
  }
  __syncthreads();

  // flush: ONE global atomic per row (and per col if off-diagonal)
  if (t < 128) {
    atomicAdd(&unsim[i0 + t], rsumS[t]);
  } else if (offdiag) {
    atomicAdd(&unsim[j0 + (t - 128)], csumS[t - 128]);
  }
  // flush positive records: one global cursor atomic per block
  int total = posCnt < PCAP ? posCnt : PCAP;
  if (t == 0) gbaseS = atomicAdd(pcur, total);
  __syncthreads();
  for (int e = t; e < total; e += 256) posBuf[gbaseS + e] = posS[e];
}

// ---------------------------------------------------------------------------
// Kernel 3: stream positive records: term = log(exp(s) + unsim[idx]) - s,
// finalize fused via last-block-done pattern.
__global__ __launch_bounds__(256) void pass3_kernel(
    const uint2* __restrict__ posBuf, int* __restrict__ pcur,
    const float* __restrict__ unsim, float* __restrict__ accum,
    float* __restrict__ out) {
  int n = *pcur;
  float local = 0.f;
  int stride = 256 * gridDim.x;
  for (int p = blockIdx.x * 256 + threadIdx.x; p < n; p += stride) {
    uint2 e = posBuf[p];
    float s = __uint_as_float(e.y);
    local += logf(__expf(s) + unsim[e.x]) - s;
  }
  __shared__ float red[4];
#pragma unroll
  for (int msk = 1; msk < 64; msk <<= 1) local += __shfl_xor(local, msk);
  int lane = threadIdx.x & 63, w = threadIdx.x >> 6;
  if (lane == 0) red[w] = local;
  __syncthreads();
  if (threadIdx.x == 0) {
    atomicAdd(&accum[0], red[0] + red[1] + red[2] + red[3]);
    __threadfence();
    int* done = (int*)&accum[2];
    if (atomicAdd(done, 1) == (int)gridDim.x - 1) {
      float ls = __hip_atomic_load(&accum[0], __ATOMIC_ACQUIRE,
                                   __HIP_MEMORY_SCOPE_AGENT);
      out[0] = ls / (float)n;
    }
  }
}

// ---------------------------------------------------------------------------
extern "C" void kernel_launch(void* const* d_in, const int* in_sizes, int n_in,
                              void* d_out, int out_size, void* d_ws,
                              size_t ws_size, hipStream_t stream) {
  const float* X = (const float*)d_in[0];
  const int* lab = (const int*)d_in[1];
  float* out = (float*)d_out;

  const int N = in_sizes[1];  // 8192; D fixed at 128

  // workspace layout
  unsigned char* Y8 = (unsigned char*)d_ws;       // N*128 fp8 (1 MB)
  float* unsim = (float*)(Y8 + (size_t)N * 128);  // N f32
  float* accum = unsim + N;                       // [0] loss, [2] done ctr
  int* pcur = (int*)(accum + 6);                  // record cursor (+ pad)
  uint2* posBuf = (uint2*)(pcur + 2);             // ~516k entries

  const float inv_sqrtT = 2.2360679775f;  // 1/sqrt(0.2)
  norm_kernel<<<N / 4, 256, 0, stream>>>(X, Y8, unsim, accum, inv_sqrtT);

  const int nt = N / 128;              // 64 tiles per dim
  const int nblk = nt * (nt + 1) / 2;  // 2080 upper-tri tile pairs
  pass1_kernel<<<nblk, 256, 0, stream>>>(Y8, lab, unsim, posBuf, pcur, nt);
  pass3_kernel<<<512, 256, 0, stream>>>(posBuf, pcur, unsim, accum, out);
}